// Round 26
// baseline (262.875 us; speedup 1.0000x reference)
//
#include <hip/hip_runtime.h>
#include <stdint.h>
#include <math.h>

typedef uint32_t u32;
typedef uint64_t u64;
typedef unsigned short u16;

#define B_T    16384
#define DD     512
#define NE     64
#define KCAP   512
#define TWO_D  1024

typedef __attribute__((ext_vector_type(8))) short bf16x8;
typedef __attribute__((ext_vector_type(4))) float f32x4;
typedef __attribute__((ext_vector_type(4))) u32 u32x4;

static __device__ __forceinline__ u32 mono_of(float s) {
  u32 b = __float_as_uint(s);
  return (b & 0x80000000u) ? ~b : (b | 0x80000000u);
}
static __device__ __forceinline__ float score_from_mono(u32 m) {
  u32 b = (m & 0x80000000u) ? (m ^ 0x80000000u) : ~m;
  return __uint_as_float(b);
}
static __device__ __forceinline__ u16 f2bf(float f) {
  u32 b = __float_as_uint(f);
  b += 0x7FFFu + ((b >> 16) & 1u);
  return (u16)(b >> 16);
}
static __device__ __forceinline__ u32 f2bf2(float lo, float hi) {
  return (u32)f2bf(lo) | ((u32)f2bf(hi) << 16);
}
static __device__ __forceinline__ float bf2f(u32 u) {
  return __uint_as_float(u << 16);
}
static __device__ __forceinline__ u32 cvtpk(float lo, float hi) {
  u32 r;
  asm("v_cvt_pk_bf16_f32 %0, %1, %2" : "=v"(r) : "v"(lo), "v"(hi));
  return r;
}
// async 16B global->LDS copy (dest: wave-uniform base + lane*16; src per-lane)
static __device__ __forceinline__ void gload_lds16(const u16* g, u16* l) {
  __builtin_amdgcn_global_load_lds(
      (const __attribute__((address_space(1))) u32*)(g),
      (__attribute__((address_space(3))) u32*)(l), 16, 0, 0);
}
static __device__ __forceinline__ bf16x8 negbf8(bf16x8 v) {
  u32x4 u;
  u32x4 s = *reinterpret_cast<u32x4*>(&v);
  u[0] = s[0] ^ 0x80008000u;
  u[1] = s[1] ^ 0x80008000u;
  u[2] = s[2] ^ 0x80008000u;
  u[3] = s[3] ^ 0x80008000u;
  return *reinterpret_cast<bf16x8*>(&u);
}

// ---------------------------------------------------------------- K13: fused k1 (gate, FROZEN
// arithmetic, 64-wide k-chunks -> 24KB LDS) and k3 (W -> bf16 transposed).
// Blocks [0,512) = gate, [512, 512+8192) = wtrans. Arena 24576 B -> 6 blocks/CU.
__global__ __launch_bounds__(256) void k13_fused(
    const float* __restrict__ x, const float* __restrict__ gw,
    float* __restrict__ scoresT, u16* __restrict__ xrb, u16* __restrict__ xib,
    const float* __restrict__ w, u16* __restrict__ wrT, u16* __restrict__ wiT) {
  __shared__ __align__(16) char smem[24576];
  const int tid = threadIdx.x;

  if (blockIdx.x < 512) {
    // ---------------- k1 body (bit-identical FMA order; 64-wide chunks) ----------------
    float (*xs)[32] = reinterpret_cast<float(*)[32]>(smem);           // 8 KB
    float (*gs)[64] = reinterpret_cast<float(*)[64]>(smem + 8192);    // 16 KB
    const int tb  = blockIdx.x * 32;
    const int tx = tid & 7, ty = tid >> 3;

    float accC[2][4];
    float accT[2][4];
#pragma unroll
    for (int i = 0; i < 2; ++i)
#pragma unroll
      for (int j = 0; j < 4; ++j) { accC[i][j] = 0.f; accT[i][j] = 0.f; }

    for (int c = 0; c < 16; ++c) {
      const int k0 = c * 64;
      {
        const int t = tid & 31, ks = (tid >> 5) * 8;
        const float* src = x + (size_t)(tb + t) * TWO_D + k0 + ks;
        u32 rr[2], ii[2];
#pragma unroll
        for (int i = 0; i < 2; ++i) {
          float4 v = reinterpret_cast<const float4*>(src)[i];
          xs[ks + i * 4 + 0][t] = v.x;
          xs[ks + i * 4 + 1][t] = v.y;
          xs[ks + i * 4 + 2][t] = v.z;
          xs[ks + i * 4 + 3][t] = v.w;
          rr[i] = f2bf2(v.x, v.z);
          ii[i] = f2bf2(v.y, v.w);
        }
        const size_t xoff = (size_t)(tb + t) * 512 + c * 32 + (ks >> 1);
        uint2 wr, wi;
        wr.x = rr[0]; wr.y = rr[1];
        wi.x = ii[0]; wi.y = ii[1];
        *reinterpret_cast<uint2*>(xrb + xoff) = wr;
        *reinterpret_cast<uint2*>(xib + xoff) = wi;

        const float4* gsrc = reinterpret_cast<const float4*>(gw + (size_t)k0 * 64);
        float4* gdst = reinterpret_cast<float4*>(&gs[0][0]);
#pragma unroll
        for (int i = 0; i < 4; ++i) gdst[tid + i * 256] = gsrc[tid + i * 256];
      }
      __syncthreads();
      for (int k = 0; k < 64; ++k) {
        float4 a4 = *reinterpret_cast<float4*>(&xs[k][tx * 4]);
        float2 b2 = *reinterpret_cast<float2*>(&gs[k][ty * 2]);
        float av[4] = {a4.x, a4.y, a4.z, a4.w};
        float bv[2] = {b2.x, b2.y};
#pragma unroll
        for (int i = 0; i < 2; ++i)
#pragma unroll
          for (int j = 0; j < 4; ++j) accC[i][j] = fmaf(bv[i], av[j], accC[i][j]);
      }
      __syncthreads();
      // kc=512 seam after chunk 7 (k=512), final fold after chunk 15 (unchanged order)
      if (c == 7 || c == 15) {
#pragma unroll
        for (int i = 0; i < 2; ++i)
#pragma unroll
          for (int j = 0; j < 4; ++j) {
            accT[i][j] = accT[i][j] + accC[i][j];
            accC[i][j] = 0.f;
          }
      }
    }
#pragma unroll
    for (int i = 0; i < 2; ++i) {
      float4 v = make_float4(accT[i][0], accT[i][1], accT[i][2], accT[i][3]);
      *reinterpret_cast<float4*>(&scoresT[(size_t)(ty * 2 + i) * B_T + tb + tx * 4]) = v;
    }
  } else {
    // ---------------- k3 body (byte-identical arithmetic) ----------------
    float (*fr)[33] = reinterpret_cast<float(*)[33]>(smem);           // 8448 B
    float (*fi)[33] = reinterpret_cast<float(*)[33]>(smem + 8448);    // 8448 B
    const int bid = blockIdx.x - 512;
    const int e = bid >> 7, tile = bid & 127;
    const int d0 = (tile >> 4) * 64, f0 = (tile & 15) * 32;
    {
      const int row = tid >> 2, lane4 = tid & 3;
      const float* src = w + ((size_t)(e * 512 + d0 + row)) * 1024 + f0 * 2 + lane4 * 16;
#pragma unroll
      for (int i = 0; i < 4; ++i) {
        float4 v = reinterpret_cast<const float4*>(src)[i];
        int fl = lane4 * 8 + 2 * i;
        fr[row][fl] = v.x;      fi[row][fl] = v.y;
        fr[row][fl + 1] = v.z;  fi[row][fl + 1] = v.w;
      }
    }
    __syncthreads();
    {
      const int f = tid >> 3, dg = tid & 7;
      u32 pr[4], pi[4];
#pragma unroll
      for (int j = 0; j < 4; ++j) {
        float r0 = fr[dg * 8 + 2 * j][f],     i0 = fi[dg * 8 + 2 * j][f];
        float r1 = fr[dg * 8 + 2 * j + 1][f], i1 = fi[dg * 8 + 2 * j + 1][f];
        pr[j] = f2bf2(r0, r1);
        pi[j] = f2bf2(i0, i1);
      }
      const size_t off = ((size_t)e * 512 + f0 + f) * 512 + d0 + dg * 8;
      uint4 vr, vi;
      vr.x = pr[0]; vr.y = pr[1]; vr.z = pr[2]; vr.w = pr[3];
      vi.x = pi[0]; vi.y = pi[1]; vi.z = pi[2]; vi.w = pi[3];
      *reinterpret_cast<uint4*>(wrT + off) = vr;
      *reinterpret_cast<uint4*>(wiT + off) = vi;
    }
  }
}

// ---------------------------------------------------------------- K2: top-k (rank-by-count) + fused invert
__global__ __launch_bounds__(1024) void k2_topk(const float* __restrict__ scoresT,
                                                int* __restrict__ topk_idx,
                                                float* __restrict__ topk_scr,
                                                int* __restrict__ counts,
                                                int* __restrict__ entries) {
  const int e = blockIdx.x, tid = threadIdx.x;
  const float* row = scoresT + (size_t)e * B_T;
  __shared__ u32 keys[B_T];
  __shared__ u32 hist[256];
  __shared__ u32 s_prefix, s_r;
  __shared__ u32 cnt_gt, cnt_eq;
  __shared__ u64 skey[512];
  __shared__ u32 tie[512];

#pragma unroll
  for (int i = 0; i < 4; ++i) {
    int v4 = i * 1024 + tid;
    float4 v = reinterpret_cast<const float4*>(row)[v4];
    keys[v4 * 4 + 0] = mono_of(v.x);
    keys[v4 * 4 + 1] = mono_of(v.y);
    keys[v4 * 4 + 2] = mono_of(v.z);
    keys[v4 * 4 + 3] = mono_of(v.w);
  }
  if (tid == 0) { s_prefix = 0; s_r = KCAP; cnt_gt = 0; cnt_eq = 0; }
  u32 prefmask = 0;
  __syncthreads();

  for (int pass = 0; pass < 4; ++pass) {
    const int shift = 24 - 8 * pass;
    if (tid < 256) hist[tid] = 0;
    __syncthreads();
    const u32 prefix = s_prefix;
    for (int t = tid; t < B_T; t += 1024) {
      u32 m = keys[t];
      if ((m & prefmask) == prefix) atomicAdd(&hist[(m >> shift) & 0xFFu], 1u);
    }
    __syncthreads();
    if (tid == 0) {
      u32 r = s_r, cum = 0;
      int sel = 0;
      for (int b = 255; b >= 0; --b) {
        if (cum + hist[b] >= r) { sel = b; s_r = r - cum; break; }
        cum += hist[b];
      }
      s_prefix = prefix | ((u32)sel << shift);
    }
    prefmask |= (0xFFu << shift);
    __syncthreads();
  }

  const u32 kmono = s_prefix;
  const u32 rneed = s_r;

  for (int t = tid; t < B_T; t += 1024) {
    u32 m = keys[t];
    if (m > kmono) {
      u32 p = atomicAdd(&cnt_gt, 1u);
      if (p < 512) skey[p] = ((u64)(~m) << 32) | (u32)t;
    } else if (m == kmono) {
      u32 p = atomicAdd(&cnt_eq, 1u);
      if (p < 512) tie[p] = (u32)t;
    }
  }
  __syncthreads();

  const u32 ngt = cnt_gt;
  const u32 ne = cnt_eq < 512u ? cnt_eq : 512u;
  if (tid < ne) {
    u32 my = tie[tid];
    u32 rank = 0;
    for (u32 j = 0; j < ne; ++j) rank += (tie[j] < my) ? 1u : 0u;
    if (rank < rneed) skey[ngt + rank] = ((u64)(~kmono) << 32) | my;
  }
  __syncthreads();

  if (tid < 512) {
    u64 my = skey[tid];
    u32 rank = 0;
    for (int j = 0; j < 512; ++j) rank += (skey[j] < my) ? 1u : 0u;
    u32 idx = (u32)my;
    u32 m = ~((u32)(my >> 32));
    topk_idx[e * KCAP + rank] = (int)idx;
    topk_scr[e * KCAP + rank] = score_from_mono(m);
    int pos = atomicAdd(&counts[idx], 1);
    entries[idx * 64 + pos] = (int)(rank * 64 + e);
  }
}

// ---------------------------------------------------------------- K4 (preconv): single-buffer, 2 blocks/CU
// (256,2) is the proven no-spill point: VGPR=100; (256,3)->84 spills,
// (256,4)->64 spills catastrophically. Locked.
__global__ __launch_bounds__(256, 2) void k4_pre(
    const u16* __restrict__ xrb, const u16* __restrict__ xib,
    const int* __restrict__ topk_idx, const float* __restrict__ topk_scr,
    const u16* __restrict__ wrT, const u16* __restrict__ wiT,
    u16* __restrict__ yrw, u16* __restrict__ yiw) {
  const int bid = blockIdx.x;
  const int xcd = bid & 7, q = bid >> 3, t = q & 15, g = q >> 4;
  const int e = g * 8 + xcd;
  const int mb = t & 3, fb = t >> 2;
  const int m0 = mb * 128, f0 = fb * 128;

  __shared__ __align__(16) u16 Ar[4096];
  __shared__ __align__(16) u16 Ai[4096];
  __shared__ __align__(16) u16 Bu[4096];
  __shared__ __align__(16) u16 Bv[4096];
  __shared__ int tok[128];
  __shared__ float scr[128];

  const int tid = threadIdx.x;
  if (tid < 128) {
    tok[tid] = topk_idx[e * KCAP + m0 + tid];
    scr[tid] = topk_scr[e * KCAP + m0 + tid];
  }
  __syncthreads();

  const int r0  = tid & 127;
  const int ka0 = (tid >> 7) * 8;
  const int ka1 = ka0 + 16;
  const size_t brow = ((size_t)e * 512 + f0 + r0) * 512;
  const size_t arow = (size_t)tok[r0] * 512;
  const int wv = tid >> 6, ln = tid & 63;
  const int d0 = wv * 512;
  const int d1 = 2048 + wv * 512;

  const int mbase = (wv >> 1) * 64, nbase = (wv & 1) * 64;
  const int frow = ln & 15, fq = ln >> 4;
  const int ra = fq * 1024 + (mbase + frow) * 8;
  const int rb = fq * 1024 + (nbase + frow) * 8;

  f32x4 accR[4][4] = {};
  f32x4 accI[4][4] = {};

  for (int step = 0; step < 16; ++step) {
    const int k0 = step * 32;
    gload_lds16(wrT + brow + k0 + ka0, Bu + d0);
    gload_lds16(wrT + brow + k0 + ka1, Bu + d1);
    gload_lds16(wiT + brow + k0 + ka0, Bv + d0);
    gload_lds16(wiT + brow + k0 + ka1, Bv + d1);
    gload_lds16(xrb + arow + k0 + ka0, Ar + d0);
    gload_lds16(xrb + arow + k0 + ka1, Ar + d1);
    gload_lds16(xib + arow + k0 + ka0, Ai + d0);
    gload_lds16(xib + arow + k0 + ka1, Ai + d1);
    __syncthreads();

    bf16x8 ar[4], ai[4], bu[4], bv[4];
#pragma unroll
    for (int m = 0; m < 4; ++m) {
      ar[m] = *reinterpret_cast<const bf16x8*>(&Ar[ra + m * 128]);
      ai[m] = *reinterpret_cast<const bf16x8*>(&Ai[ra + m * 128]);
    }
#pragma unroll
    for (int n = 0; n < 4; ++n) {
      bu[n] = *reinterpret_cast<const bf16x8*>(&Bu[rb + n * 128]);
      bv[n] = *reinterpret_cast<const bf16x8*>(&Bv[rb + n * 128]);
    }
#pragma unroll
    for (int m = 0; m < 4; ++m)
#pragma unroll
      for (int n = 0; n < 4; ++n) {
        bf16x8 bw = negbf8(bv[n]);
        accR[m][n] = __builtin_amdgcn_mfma_f32_16x16x32_bf16(ar[m], bu[n], accR[m][n], 0, 0, 0);
        accR[m][n] = __builtin_amdgcn_mfma_f32_16x16x32_bf16(ai[m], bw,    accR[m][n], 0, 0, 0);
        accI[m][n] = __builtin_amdgcn_mfma_f32_16x16x32_bf16(ar[m], bv[n], accI[m][n], 0, 0, 0);
        accI[m][n] = __builtin_amdgcn_mfma_f32_16x16x32_bf16(ai[m], bu[n], accI[m][n], 0, 0, 0);
      }
    __syncthreads();
  }

  const int rr = fq * 4;
#pragma unroll
  for (int m = 0; m < 4; ++m) {
#pragma unroll
    for (int r = 0; r < 4; ++r) {
      const int jl = mbase + m * 16 + rr + r;
      const float ww = scr[jl];
      const size_t ybase = ((size_t)e * KCAP + m0 + jl) * DD;
#pragma unroll
      for (int n = 0; n < 4; ++n) {
        const int fg = f0 + nbase + n * 16 + frow;
        yrw[ybase + fg] = f2bf(accR[m][n][r] * ww);
        yiw[ybase + fg] = f2bf(accI[m][n][r] * ww);
      }
    }
  }
}

// ---------------------------------------------------------------- K4 (fallback): reg-staged
__global__ __launch_bounds__(256, 2) void k4_fb(
    const float* __restrict__ x, const int* __restrict__ topk_idx,
    const float* __restrict__ topk_scr, const u16* __restrict__ wrT,
    const u16* __restrict__ wiT, u16* __restrict__ yrw, u16* __restrict__ yiw) {
  const int bid = blockIdx.x;
  const int xcd = bid & 7, q = bid >> 3, t = q & 15, g = q >> 4;
  const int e = g * 8 + xcd;
  const int mb = t & 3, fb = t >> 2;
  const int m0 = mb * 128, f0 = fb * 128;

  __shared__ __align__(16) u16 Ar[4096];
  __shared__ __align__(16) u16 Ai[4096];
  __shared__ __align__(16) u16 Bu[4096];
  __shared__ __align__(16) u16 Bv[4096];
  __shared__ int tok[128];
  __shared__ float scr[128];

  const int tid = threadIdx.x;
  if (tid < 128) {
    tok[tid] = topk_idx[e * KCAP + m0 + tid];
    scr[tid] = topk_scr[e * KCAP + m0 + tid];
  }
  __syncthreads();

  const int r0  = tid & 127;
  const int ka0 = (tid >> 7) * 8;
  const int ka1 = ka0 + 16;
  const size_t brow = ((size_t)e * 512 + f0 + r0) * 512;
  const int wv = tid >> 6, ln = tid & 63;
  const int d0 = wv * 512;
  const int d1 = 2048 + wv * 512;

  const int row = tid >> 1, half = tid & 1;
  const float* arow_f = x + (size_t)tok[row] * TWO_D + half * 32;

  const int mbase = (wv >> 1) * 64, nbase = (wv & 1) * 64;
  const int frow = ln & 15, fq = ln >> 4;
  const int ra = fq * 1024 + (mbase + frow) * 8;
  const int rb = fq * 1024 + (nbase + frow) * 8;

  f32x4 accR[4][4] = {};
  f32x4 accI[4][4] = {};

  for (int step = 0; step < 16; ++step) {
    const int k0 = step * 32;
    gload_lds16(wrT + brow + k0 + ka0, Bu + d0);
    gload_lds16(wrT + brow + k0 + ka1, Bu + d1);
    gload_lds16(wiT + brow + k0 + ka0, Bv + d0);
    gload_lds16(wiT + brow + k0 + ka1, Bv + d1);
    {
      const float4* ap = reinterpret_cast<const float4*>(arow_f + (size_t)k0 * 2);
      u32 xr[8], xi[8];
#pragma unroll
      for (int i = 0; i < 8; ++i) {
        float4 v = ap[i];
        xr[i] = cvtpk(v.x, v.z);
        xi[i] = cvtpk(v.y, v.w);
      }
      uint4 wa, wb;
      wa.x = xr[0]; wa.y = xr[1]; wa.z = xr[2]; wa.w = xr[3];
      wb.x = xr[4]; wb.y = xr[5]; wb.z = xr[6]; wb.w = xr[7];
      *reinterpret_cast<uint4*>(&Ar[(2 * half) * 1024 + row * 8]) = wa;
      *reinterpret_cast<uint4*>(&Ar[(2 * half + 1) * 1024 + row * 8]) = wb;
      wa.x = xi[0]; wa.y = xi[1]; wa.z = xi[2]; wa.w = xi[3];
      wb.x = xi[4]; wb.y = xi[5]; wb.z = xi[6]; wb.w = xi[7];
      *reinterpret_cast<uint4*>(&Ai[(2 * half) * 1024 + row * 8]) = wa;
      *reinterpret_cast<uint4*>(&Ai[(2 * half + 1) * 1024 + row * 8]) = wb;
    }
    __syncthreads();

    bf16x8 ar[4], ai[4], bu[4], bv[4];
#pragma unroll
    for (int m = 0; m < 4; ++m) {
      ar[m] = *reinterpret_cast<const bf16x8*>(&Ar[ra + m * 128]);
      ai[m] = *reinterpret_cast<const bf16x8*>(&Ai[ra + m * 128]);
    }
#pragma unroll
    for (int n = 0; n < 4; ++n) {
      bu[n] = *reinterpret_cast<const bf16x8*>(&Bu[rb + n * 128]);
      bv[n] = *reinterpret_cast<const bf16x8*>(&Bv[rb + n * 128]);
    }
#pragma unroll
    for (int m = 0; m < 4; ++m)
#pragma unroll
      for (int n = 0; n < 4; ++n) {
        bf16x8 bw = negbf8(bv[n]);
        accR[m][n] = __builtin_amdgcn_mfma_f32_16x16x32_bf16(ar[m], bu[n], accR[m][n], 0, 0, 0);
        accR[m][n] = __builtin_amdgcn_mfma_f32_16x16x32_bf16(ai[m], bw,    accR[m][n], 0, 0, 0);
        accI[m][n] = __builtin_amdgcn_mfma_f32_16x16x32_bf16(ar[m], bv[n], accI[m][n], 0, 0, 0);
        accI[m][n] = __builtin_amdgcn_mfma_f32_16x16x32_bf16(ai[m], bu[n], accI[m][n], 0, 0, 0);
      }
    __syncthreads();
  }

  const int rr = fq * 4;
#pragma unroll
  for (int m = 0; m < 4; ++m) {
#pragma unroll
    for (int r = 0; r < 4; ++r) {
      const int jl = mbase + m * 16 + rr + r;
      const float ww = scr[jl];
      const size_t ybase = ((size_t)e * KCAP + m0 + jl) * DD;
#pragma unroll
      for (int n = 0; n < 4; ++n) {
        const int fg = f0 + nbase + n * 16 + frow;
        yrw[ybase + fg] = f2bf(accR[m][n][r] * ww);
        yiw[ybase + fg] = f2bf(accI[m][n][r] * ww);
      }
    }
  }
}

// ---------------------------------------------------------------- K5: gather + GELU
#define GELU(z) (0.5f * (z) * (1.0f + erff((z)*0.70710678118654752440f)))
__global__ __launch_bounds__(256) void k5_gather(
    const u16* __restrict__ yrw, const u16* __restrict__ yiw,
    const int* __restrict__ counts, const int* __restrict__ entries,
    const float* __restrict__ bias, float* __restrict__ out) {
  const int t = blockIdx.x * 2 + (threadIdx.x >> 7);
  const int lane = threadIdx.x & 127;
  const int c = counts[t];
  const float inv = 1.0f / (float)(c > 0 ? c : 1);
  const int f4 = lane * 4;
  float sr[4] = {0.f, 0.f, 0.f, 0.f}, si[4] = {0.f, 0.f, 0.f, 0.f};
  for (int i = 0; i < c; ++i) {
    int srcrow = entries[t * 64 + i];
    size_t off = (size_t)srcrow * DD + f4;
    uint2 pr = *reinterpret_cast<const uint2*>(yrw + off);
    uint2 pi = *reinterpret_cast<const uint2*>(yiw + off);
    sr[0] += bf2f(pr.x & 0xFFFFu); sr[1] += bf2f(pr.x >> 16);
    sr[2] += bf2f(pr.y & 0xFFFFu); sr[3] += bf2f(pr.y >> 16);
    si[0] += bf2f(pi.x & 0xFFFFu); si[1] += bf2f(pi.x >> 16);
    si[2] += bf2f(pi.y & 0xFFFFu); si[3] += bf2f(pi.y >> 16);
  }
  const float b0 = bias[f4], b1 = bias[f4 + 1], b2 = bias[f4 + 2], b3 = bias[f4 + 3];
  float4 o1, o2;
  o1.x = GELU(sr[0] * inv + b0); o1.y = GELU(si[0] * inv + b0);
  o1.z = GELU(sr[1] * inv + b1); o1.w = GELU(si[1] * inv + b1);
  o2.x = GELU(sr[2] * inv + b2); o2.y = GELU(si[2] * inv + b2);
  o2.z = GELU(sr[3] * inv + b3); o2.w = GELU(si[3] * inv + b3);
  float* dst = out + (size_t)t * TWO_D + (size_t)f4 * 2;
  reinterpret_cast<float4*>(dst)[0] = o1;
  reinterpret_cast<float4*>(dst)[1] = o2;
}

// ---------------------------------------------------------------- launch
extern "C" void kernel_launch(void* const* d_in, const int* in_sizes, int n_in,
                              void* d_out, int out_size, void* d_ws, size_t ws_size,
                              hipStream_t stream) {
  const float* x    = (const float*)d_in[0];
  const float* gw   = (const float*)d_in[1];
  const float* w    = (const float*)d_in[2];
  const float* bias = (const float*)d_in[3];
  float* out = (float*)d_out;

  char* ws = (char*)d_ws;
  u16*   yrw     = (u16*)(ws);                  //  32 MiB (aliases scoresT)
  float* scoresT = (float*)(ws);                //   4 MiB (dead before k4)
  u16*   yiw     = (u16*)(ws + 33554432);       //  32 MiB
  int*   tidx    = (int*)(ws + 67108864);       //  128 KiB
  float* tscr    = (float*)(ws + 67239936);     //  128 KiB
  int*   counts  = (int*)(ws + 67371008);       //  64 KiB
  int*   entries = (int*)(ws + 67436544);       //   4 MiB
  u16*   wrT     = (u16*)(ws + 71630848);       //  32 MiB
  u16*   wiT     = (u16*)(ws + 105185280);      //  32 MiB  (end: 138,739,712)
  u16*   xrb     = (u16*)(ws + 138739712);      //  16 MiB  (preconv only)
  u16*   xib     = (u16*)(ws + 155516928);      //  16 MiB  (end: 172,294,144)

  const bool preconv = ws_size >= 172294144ull;

  hipMemsetAsync(counts, 0, B_T * sizeof(int), stream);
  if (preconv) {
    k13_fused<<<512 + NE * 128, 256, 0, stream>>>(x, gw, scoresT, xrb, xib, w, wrT, wiT);
    k2_topk<<<NE, 1024, 0, stream>>>(scoresT, tidx, tscr, counts, entries);
    k4_pre<<<1024, 256, 0, stream>>>(xrb, xib, tidx, tscr, wrT, wiT, yrw, yiw);
  } else {
    k13_fused<<<512 + NE * 128, 256, 0, stream>>>(x, gw, scoresT,
                                                  (u16*)(ws + 33554432),
                                                  (u16*)(ws + 33554432 + 16777216),
                                                  w, wrT, wiT);
    k2_topk<<<NE, 1024, 0, stream>>>(scoresT, tidx, tscr, counts, entries);
    k4_fb<<<1024, 256, 0, stream>>>(x, tidx, tscr, wrT, wiT, yrw, yiw);
  }
  k5_gather<<<B_T / 2, 256, 0, stream>>>(yrw, yiw, counts, entries, bias, out);
}

// Round 27
// 254.754 us; speedup vs baseline: 1.0319x; 1.0319x over previous
//
#include <hip/hip_runtime.h>
#include <stdint.h>
#include <math.h>

typedef uint32_t u32;
typedef uint64_t u64;
typedef unsigned short u16;

#define B_T    16384
#define DD     512
#define NE     64
#define KCAP   512
#define TWO_D  1024

typedef __attribute__((ext_vector_type(8))) short bf16x8;
typedef __attribute__((ext_vector_type(4))) float f32x4;
typedef __attribute__((ext_vector_type(4))) u32 u32x4;

static __device__ __forceinline__ u32 mono_of(float s) {
  u32 b = __float_as_uint(s);
  return (b & 0x80000000u) ? ~b : (b | 0x80000000u);
}
static __device__ __forceinline__ float score_from_mono(u32 m) {
  u32 b = (m & 0x80000000u) ? (m ^ 0x80000000u) : ~m;
  return __uint_as_float(b);
}
static __device__ __forceinline__ u16 f2bf(float f) {
  u32 b = __float_as_uint(f);
  b += 0x7FFFu + ((b >> 16) & 1u);
  return (u16)(b >> 16);
}
static __device__ __forceinline__ u32 f2bf2(float lo, float hi) {
  return (u32)f2bf(lo) | ((u32)f2bf(hi) << 16);
}
static __device__ __forceinline__ float bf2f(u32 u) {
  return __uint_as_float(u << 16);
}
static __device__ __forceinline__ u32 cvtpk(float lo, float hi) {
  u32 r;
  asm("v_cvt_pk_bf16_f32 %0, %1, %2" : "=v"(r) : "v"(lo), "v"(hi));
  return r;
}
// async 16B global->LDS copy (dest: wave-uniform base + lane*16; src per-lane)
static __device__ __forceinline__ void gload_lds16(const u16* g, u16* l) {
  __builtin_amdgcn_global_load_lds(
      (const __attribute__((address_space(1))) u32*)(g),
      (__attribute__((address_space(3))) u32*)(l), 16, 0, 0);
}
static __device__ __forceinline__ bf16x8 negbf8(bf16x8 v) {
  u32x4 u;
  u32x4 s = *reinterpret_cast<u32x4*>(&v);
  u[0] = s[0] ^ 0x80008000u;
  u[1] = s[1] ^ 0x80008000u;
  u[2] = s[2] ^ 0x80008000u;
  u[3] = s[3] ^ 0x80008000u;
  return *reinterpret_cast<bf16x8*>(&u);
}

// ---------------------------------------------------------------- K13: fused k1 (gate, FROZEN
// arithmetic, + x->bf16 split) and k3 (W -> bf16 transposed). Independent work,
// one launch: blocks [0,512) = gate, [512, 512+8192) = wtrans.
// (R26 showed 24KB/64-chunk variant is SLOWER: k1 is chain-bound, not
// occupancy-bound. This 48KB/128-chunk version measured 254.8 us total.)
__global__ __launch_bounds__(256) void k13_fused(
    const float* __restrict__ x, const float* __restrict__ gw,
    float* __restrict__ scoresT, u16* __restrict__ xrb, u16* __restrict__ xib,
    const float* __restrict__ w, u16* __restrict__ wrT, u16* __restrict__ wiT) {
  __shared__ __align__(16) char smem[49152];
  const int tid = threadIdx.x;

  if (blockIdx.x < 512) {
    // ---------------- k1 body (byte-identical arithmetic) ----------------
    float (*xs)[32] = reinterpret_cast<float(*)[32]>(smem);            // 16 KB
    float (*gs)[64] = reinterpret_cast<float(*)[64]>(smem + 16384);    // 32 KB
    const int tb  = blockIdx.x * 32;
    const int tx = tid & 7, ty = tid >> 3;

    float accC[2][4];
    float accT[2][4];
#pragma unroll
    for (int i = 0; i < 2; ++i)
#pragma unroll
      for (int j = 0; j < 4; ++j) { accC[i][j] = 0.f; accT[i][j] = 0.f; }

    for (int c = 0; c < 8; ++c) {
      const int k0 = c * 128;
      {
        const int t = tid & 31, ks = (tid >> 5) * 16;
        const float* src = x + (size_t)(tb + t) * TWO_D + k0 + ks;
        u32 rr[4], ii[4];
#pragma unroll
        for (int i = 0; i < 4; ++i) {
          float4 v = reinterpret_cast<const float4*>(src)[i];
          xs[ks + i * 4 + 0][t] = v.x;
          xs[ks + i * 4 + 1][t] = v.y;
          xs[ks + i * 4 + 2][t] = v.z;
          xs[ks + i * 4 + 3][t] = v.w;
          rr[i] = f2bf2(v.x, v.z);
          ii[i] = f2bf2(v.y, v.w);
        }
        const size_t xoff = (size_t)(tb + t) * 512 + c * 64 + (ks >> 1);
        uint4 wr, wi;
        wr.x = rr[0]; wr.y = rr[1]; wr.z = rr[2]; wr.w = rr[3];
        wi.x = ii[0]; wi.y = ii[1]; wi.z = ii[2]; wi.w = ii[3];
        *reinterpret_cast<uint4*>(xrb + xoff) = wr;
        *reinterpret_cast<uint4*>(xib + xoff) = wi;

        const float4* gsrc = reinterpret_cast<const float4*>(gw + (size_t)k0 * 64);
        float4* gdst = reinterpret_cast<float4*>(&gs[0][0]);
#pragma unroll
        for (int i = 0; i < 8; ++i) gdst[tid + i * 256] = gsrc[tid + i * 256];
      }
      __syncthreads();
      for (int k = 0; k < 128; ++k) {
        float4 a4 = *reinterpret_cast<float4*>(&xs[k][tx * 4]);
        float2 b2 = *reinterpret_cast<float2*>(&gs[k][ty * 2]);
        float av[4] = {a4.x, a4.y, a4.z, a4.w};
        float bv[2] = {b2.x, b2.y};
#pragma unroll
        for (int i = 0; i < 2; ++i)
#pragma unroll
          for (int j = 0; j < 4; ++j) accC[i][j] = fmaf(bv[i], av[j], accC[i][j]);
      }
      __syncthreads();
      if (c == 3 || c == 7) {
#pragma unroll
        for (int i = 0; i < 2; ++i)
#pragma unroll
          for (int j = 0; j < 4; ++j) {
            accT[i][j] = accT[i][j] + accC[i][j];
            accC[i][j] = 0.f;
          }
      }
    }
#pragma unroll
    for (int i = 0; i < 2; ++i) {
      float4 v = make_float4(accT[i][0], accT[i][1], accT[i][2], accT[i][3]);
      *reinterpret_cast<float4*>(&scoresT[(size_t)(ty * 2 + i) * B_T + tb + tx * 4]) = v;
    }
  } else {
    // ---------------- k3 body (byte-identical arithmetic) ----------------
    float (*fr)[33] = reinterpret_cast<float(*)[33]>(smem);           // 8448 B
    float (*fi)[33] = reinterpret_cast<float(*)[33]>(smem + 8448);    // 8448 B
    const int bid = blockIdx.x - 512;
    const int e = bid >> 7, tile = bid & 127;
    const int d0 = (tile >> 4) * 64, f0 = (tile & 15) * 32;
    {
      const int row = tid >> 2, lane4 = tid & 3;
      const float* src = w + ((size_t)(e * 512 + d0 + row)) * 1024 + f0 * 2 + lane4 * 16;
#pragma unroll
      for (int i = 0; i < 4; ++i) {
        float4 v = reinterpret_cast<const float4*>(src)[i];
        int fl = lane4 * 8 + 2 * i;
        fr[row][fl] = v.x;      fi[row][fl] = v.y;
        fr[row][fl + 1] = v.z;  fi[row][fl + 1] = v.w;
      }
    }
    __syncthreads();
    {
      const int f = tid >> 3, dg = tid & 7;
      u32 pr[4], pi[4];
#pragma unroll
      for (int j = 0; j < 4; ++j) {
        float r0 = fr[dg * 8 + 2 * j][f],     i0 = fi[dg * 8 + 2 * j][f];
        float r1 = fr[dg * 8 + 2 * j + 1][f], i1 = fi[dg * 8 + 2 * j + 1][f];
        pr[j] = f2bf2(r0, r1);
        pi[j] = f2bf2(i0, i1);
      }
      const size_t off = ((size_t)e * 512 + f0 + f) * 512 + d0 + dg * 8;
      uint4 vr, vi;
      vr.x = pr[0]; vr.y = pr[1]; vr.z = pr[2]; vr.w = pr[3];
      vi.x = pi[0]; vi.y = pi[1]; vi.z = pi[2]; vi.w = pi[3];
      *reinterpret_cast<uint4*>(wrT + off) = vr;
      *reinterpret_cast<uint4*>(wiT + off) = vi;
    }
  }
}

// ---------------------------------------------------------------- K2: top-k (rank-by-count) + fused invert
__global__ __launch_bounds__(1024) void k2_topk(const float* __restrict__ scoresT,
                                                int* __restrict__ topk_idx,
                                                float* __restrict__ topk_scr,
                                                int* __restrict__ counts,
                                                int* __restrict__ entries) {
  const int e = blockIdx.x, tid = threadIdx.x;
  const float* row = scoresT + (size_t)e * B_T;
  __shared__ u32 keys[B_T];
  __shared__ u32 hist[256];
  __shared__ u32 s_prefix, s_r;
  __shared__ u32 cnt_gt, cnt_eq;
  __shared__ u64 skey[512];
  __shared__ u32 tie[512];

#pragma unroll
  for (int i = 0; i < 4; ++i) {
    int v4 = i * 1024 + tid;
    float4 v = reinterpret_cast<const float4*>(row)[v4];
    keys[v4 * 4 + 0] = mono_of(v.x);
    keys[v4 * 4 + 1] = mono_of(v.y);
    keys[v4 * 4 + 2] = mono_of(v.z);
    keys[v4 * 4 + 3] = mono_of(v.w);
  }
  if (tid == 0) { s_prefix = 0; s_r = KCAP; cnt_gt = 0; cnt_eq = 0; }
  u32 prefmask = 0;
  __syncthreads();

  for (int pass = 0; pass < 4; ++pass) {
    const int shift = 24 - 8 * pass;
    if (tid < 256) hist[tid] = 0;
    __syncthreads();
    const u32 prefix = s_prefix;
    for (int t = tid; t < B_T; t += 1024) {
      u32 m = keys[t];
      if ((m & prefmask) == prefix) atomicAdd(&hist[(m >> shift) & 0xFFu], 1u);
    }
    __syncthreads();
    if (tid == 0) {
      u32 r = s_r, cum = 0;
      int sel = 0;
      for (int b = 255; b >= 0; --b) {
        if (cum + hist[b] >= r) { sel = b; s_r = r - cum; break; }
        cum += hist[b];
      }
      s_prefix = prefix | ((u32)sel << shift);
    }
    prefmask |= (0xFFu << shift);
    __syncthreads();
  }

  const u32 kmono = s_prefix;
  const u32 rneed = s_r;

  for (int t = tid; t < B_T; t += 1024) {
    u32 m = keys[t];
    if (m > kmono) {
      u32 p = atomicAdd(&cnt_gt, 1u);
      if (p < 512) skey[p] = ((u64)(~m) << 32) | (u32)t;
    } else if (m == kmono) {
      u32 p = atomicAdd(&cnt_eq, 1u);
      if (p < 512) tie[p] = (u32)t;
    }
  }
  __syncthreads();

  const u32 ngt = cnt_gt;
  const u32 ne = cnt_eq < 512u ? cnt_eq : 512u;
  if (tid < ne) {
    u32 my = tie[tid];
    u32 rank = 0;
    for (u32 j = 0; j < ne; ++j) rank += (tie[j] < my) ? 1u : 0u;
    if (rank < rneed) skey[ngt + rank] = ((u64)(~kmono) << 32) | my;
  }
  __syncthreads();

  if (tid < 512) {
    u64 my = skey[tid];
    u32 rank = 0;
    for (int j = 0; j < 512; ++j) rank += (skey[j] < my) ? 1u : 0u;
    u32 idx = (u32)my;
    u32 m = ~((u32)(my >> 32));
    topk_idx[e * KCAP + rank] = (int)idx;
    topk_scr[e * KCAP + rank] = score_from_mono(m);
    int pos = atomicAdd(&counts[idx], 1);
    entries[idx * 64 + pos] = (int)(rank * 64 + e);
  }
}

// ---------------------------------------------------------------- K4 (preconv): single-buffer, 2 blocks/CU
// (256,2) is the proven no-spill point: VGPR=100; (256,3)->84 spills,
// (256,4)->64 spills catastrophically. Locked.
__global__ __launch_bounds__(256, 2) void k4_pre(
    const u16* __restrict__ xrb, const u16* __restrict__ xib,
    const int* __restrict__ topk_idx, const float* __restrict__ topk_scr,
    const u16* __restrict__ wrT, const u16* __restrict__ wiT,
    u16* __restrict__ yrw, u16* __restrict__ yiw) {
  const int bid = blockIdx.x;
  const int xcd = bid & 7, q = bid >> 3, t = q & 15, g = q >> 4;
  const int e = g * 8 + xcd;
  const int mb = t & 3, fb = t >> 2;
  const int m0 = mb * 128, f0 = fb * 128;

  __shared__ __align__(16) u16 Ar[4096];
  __shared__ __align__(16) u16 Ai[4096];
  __shared__ __align__(16) u16 Bu[4096];
  __shared__ __align__(16) u16 Bv[4096];
  __shared__ int tok[128];
  __shared__ float scr[128];

  const int tid = threadIdx.x;
  if (tid < 128) {
    tok[tid] = topk_idx[e * KCAP + m0 + tid];
    scr[tid] = topk_scr[e * KCAP + m0 + tid];
  }
  __syncthreads();

  const int r0  = tid & 127;
  const int ka0 = (tid >> 7) * 8;
  const int ka1 = ka0 + 16;
  const size_t brow = ((size_t)e * 512 + f0 + r0) * 512;
  const size_t arow = (size_t)tok[r0] * 512;
  const int wv = tid >> 6, ln = tid & 63;
  const int d0 = wv * 512;
  const int d1 = 2048 + wv * 512;

  const int mbase = (wv >> 1) * 64, nbase = (wv & 1) * 64;
  const int frow = ln & 15, fq = ln >> 4;
  const int ra = fq * 1024 + (mbase + frow) * 8;
  const int rb = fq * 1024 + (nbase + frow) * 8;

  f32x4 accR[4][4] = {};
  f32x4 accI[4][4] = {};

  for (int step = 0; step < 16; ++step) {
    const int k0 = step * 32;
    gload_lds16(wrT + brow + k0 + ka0, Bu + d0);
    gload_lds16(wrT + brow + k0 + ka1, Bu + d1);
    gload_lds16(wiT + brow + k0 + ka0, Bv + d0);
    gload_lds16(wiT + brow + k0 + ka1, Bv + d1);
    gload_lds16(xrb + arow + k0 + ka0, Ar + d0);
    gload_lds16(xrb + arow + k0 + ka1, Ar + d1);
    gload_lds16(xib + arow + k0 + ka0, Ai + d0);
    gload_lds16(xib + arow + k0 + ka1, Ai + d1);
    __syncthreads();

    bf16x8 ar[4], ai[4], bu[4], bv[4];
#pragma unroll
    for (int m = 0; m < 4; ++m) {
      ar[m] = *reinterpret_cast<const bf16x8*>(&Ar[ra + m * 128]);
      ai[m] = *reinterpret_cast<const bf16x8*>(&Ai[ra + m * 128]);
    }
#pragma unroll
    for (int n = 0; n < 4; ++n) {
      bu[n] = *reinterpret_cast<const bf16x8*>(&Bu[rb + n * 128]);
      bv[n] = *reinterpret_cast<const bf16x8*>(&Bv[rb + n * 128]);
    }
#pragma unroll
    for (int m = 0; m < 4; ++m)
#pragma unroll
      for (int n = 0; n < 4; ++n) {
        bf16x8 bw = negbf8(bv[n]);
        accR[m][n] = __builtin_amdgcn_mfma_f32_16x16x32_bf16(ar[m], bu[n], accR[m][n], 0, 0, 0);
        accR[m][n] = __builtin_amdgcn_mfma_f32_16x16x32_bf16(ai[m], bw,    accR[m][n], 0, 0, 0);
        accI[m][n] = __builtin_amdgcn_mfma_f32_16x16x32_bf16(ar[m], bv[n], accI[m][n], 0, 0, 0);
        accI[m][n] = __builtin_amdgcn_mfma_f32_16x16x32_bf16(ai[m], bu[n], accI[m][n], 0, 0, 0);
      }
    __syncthreads();
  }

  const int rr = fq * 4;
#pragma unroll
  for (int m = 0; m < 4; ++m) {
#pragma unroll
    for (int r = 0; r < 4; ++r) {
      const int jl = mbase + m * 16 + rr + r;
      const float ww = scr[jl];
      const size_t ybase = ((size_t)e * KCAP + m0 + jl) * DD;
#pragma unroll
      for (int n = 0; n < 4; ++n) {
        const int fg = f0 + nbase + n * 16 + frow;
        yrw[ybase + fg] = f2bf(accR[m][n][r] * ww);
        yiw[ybase + fg] = f2bf(accI[m][n][r] * ww);
      }
    }
  }
}

// ---------------------------------------------------------------- K4 (fallback): reg-staged
__global__ __launch_bounds__(256, 2) void k4_fb(
    const float* __restrict__ x, const int* __restrict__ topk_idx,
    const float* __restrict__ topk_scr, const u16* __restrict__ wrT,
    const u16* __restrict__ wiT, u16* __restrict__ yrw, u16* __restrict__ yiw) {
  const int bid = blockIdx.x;
  const int xcd = bid & 7, q = bid >> 3, t = q & 15, g = q >> 4;
  const int e = g * 8 + xcd;
  const int mb = t & 3, fb = t >> 2;
  const int m0 = mb * 128, f0 = fb * 128;

  __shared__ __align__(16) u16 Ar[4096];
  __shared__ __align__(16) u16 Ai[4096];
  __shared__ __align__(16) u16 Bu[4096];
  __shared__ __align__(16) u16 Bv[4096];
  __shared__ int tok[128];
  __shared__ float scr[128];

  const int tid = threadIdx.x;
  if (tid < 128) {
    tok[tid] = topk_idx[e * KCAP + m0 + tid];
    scr[tid] = topk_scr[e * KCAP + m0 + tid];
  }
  __syncthreads();

  const int r0  = tid & 127;
  const int ka0 = (tid >> 7) * 8;
  const int ka1 = ka0 + 16;
  const size_t brow = ((size_t)e * 512 + f0 + r0) * 512;
  const int wv = tid >> 6, ln = tid & 63;
  const int d0 = wv * 512;
  const int d1 = 2048 + wv * 512;

  const int row = tid >> 1, half = tid & 1;
  const float* arow_f = x + (size_t)tok[row] * TWO_D + half * 32;

  const int mbase = (wv >> 1) * 64, nbase = (wv & 1) * 64;
  const int frow = ln & 15, fq = ln >> 4;
  const int ra = fq * 1024 + (mbase + frow) * 8;
  const int rb = fq * 1024 + (nbase + frow) * 8;

  f32x4 accR[4][4] = {};
  f32x4 accI[4][4] = {};

  for (int step = 0; step < 16; ++step) {
    const int k0 = step * 32;
    gload_lds16(wrT + brow + k0 + ka0, Bu + d0);
    gload_lds16(wrT + brow + k0 + ka1, Bu + d1);
    gload_lds16(wiT + brow + k0 + ka0, Bv + d0);
    gload_lds16(wiT + brow + k0 + ka1, Bv + d1);
    {
      const float4* ap = reinterpret_cast<const float4*>(arow_f + (size_t)k0 * 2);
      u32 xr[8], xi[8];
#pragma unroll
      for (int i = 0; i < 8; ++i) {
        float4 v = ap[i];
        xr[i] = cvtpk(v.x, v.z);
        xi[i] = cvtpk(v.y, v.w);
      }
      uint4 wa, wb;
      wa.x = xr[0]; wa.y = xr[1]; wa.z = xr[2]; wa.w = xr[3];
      wb.x = xr[4]; wb.y = xr[5]; wb.z = xr[6]; wb.w = xr[7];
      *reinterpret_cast<uint4*>(&Ar[(2 * half) * 1024 + row * 8]) = wa;
      *reinterpret_cast<uint4*>(&Ar[(2 * half + 1) * 1024 + row * 8]) = wb;
      wa.x = xi[0]; wa.y = xi[1]; wa.z = xi[2]; wa.w = xi[3];
      wb.x = xi[4]; wb.y = xi[5]; wb.z = xi[6]; wb.w = xi[7];
      *reinterpret_cast<uint4*>(&Ai[(2 * half) * 1024 + row * 8]) = wa;
      *reinterpret_cast<uint4*>(&Ai[(2 * half + 1) * 1024 + row * 8]) = wb;
    }
    __syncthreads();

    bf16x8 ar[4], ai[4], bu[4], bv[4];
#pragma unroll
    for (int m = 0; m < 4; ++m) {
      ar[m] = *reinterpret_cast<const bf16x8*>(&Ar[ra + m * 128]);
      ai[m] = *reinterpret_cast<const bf16x8*>(&Ai[ra + m * 128]);
    }
#pragma unroll
    for (int n = 0; n < 4; ++n) {
      bu[n] = *reinterpret_cast<const bf16x8*>(&Bu[rb + n * 128]);
      bv[n] = *reinterpret_cast<const bf16x8*>(&Bv[rb + n * 128]);
    }
#pragma unroll
    for (int m = 0; m < 4; ++m)
#pragma unroll
      for (int n = 0; n < 4; ++n) {
        bf16x8 bw = negbf8(bv[n]);
        accR[m][n] = __builtin_amdgcn_mfma_f32_16x16x32_bf16(ar[m], bu[n], accR[m][n], 0, 0, 0);
        accR[m][n] = __builtin_amdgcn_mfma_f32_16x16x32_bf16(ai[m], bw,    accR[m][n], 0, 0, 0);
        accI[m][n] = __builtin_amdgcn_mfma_f32_16x16x32_bf16(ar[m], bv[n], accI[m][n], 0, 0, 0);
        accI[m][n] = __builtin_amdgcn_mfma_f32_16x16x32_bf16(ai[m], bu[n], accI[m][n], 0, 0, 0);
      }
    __syncthreads();
  }

  const int rr = fq * 4;
#pragma unroll
  for (int m = 0; m < 4; ++m) {
#pragma unroll
    for (int r = 0; r < 4; ++r) {
      const int jl = mbase + m * 16 + rr + r;
      const float ww = scr[jl];
      const size_t ybase = ((size_t)e * KCAP + m0 + jl) * DD;
#pragma unroll
      for (int n = 0; n < 4; ++n) {
        const int fg = f0 + nbase + n * 16 + frow;
        yrw[ybase + fg] = f2bf(accR[m][n][r] * ww);
        yiw[ybase + fg] = f2bf(accI[m][n][r] * ww);
      }
    }
  }
}

// ---------------------------------------------------------------- K5: gather + GELU
#define GELU(z) (0.5f * (z) * (1.0f + erff((z)*0.70710678118654752440f)))
__global__ __launch_bounds__(256) void k5_gather(
    const u16* __restrict__ yrw, const u16* __restrict__ yiw,
    const int* __restrict__ counts, const int* __restrict__ entries,
    const float* __restrict__ bias, float* __restrict__ out) {
  const int t = blockIdx.x * 2 + (threadIdx.x >> 7);
  const int lane = threadIdx.x & 127;
  const int c = counts[t];
  const float inv = 1.0f / (float)(c > 0 ? c : 1);
  const int f4 = lane * 4;
  float sr[4] = {0.f, 0.f, 0.f, 0.f}, si[4] = {0.f, 0.f, 0.f, 0.f};
  for (int i = 0; i < c; ++i) {
    int srcrow = entries[t * 64 + i];
    size_t off = (size_t)srcrow * DD + f4;
    uint2 pr = *reinterpret_cast<const uint2*>(yrw + off);
    uint2 pi = *reinterpret_cast<const uint2*>(yiw + off);
    sr[0] += bf2f(pr.x & 0xFFFFu); sr[1] += bf2f(pr.x >> 16);
    sr[2] += bf2f(pr.y & 0xFFFFu); sr[3] += bf2f(pr.y >> 16);
    si[0] += bf2f(pi.x & 0xFFFFu); si[1] += bf2f(pi.x >> 16);
    si[2] += bf2f(pi.y & 0xFFFFu); si[3] += bf2f(pi.y >> 16);
  }
  const float b0 = bias[f4], b1 = bias[f4 + 1], b2 = bias[f4 + 2], b3 = bias[f4 + 3];
  float4 o1, o2;
  o1.x = GELU(sr[0] * inv + b0); o1.y = GELU(si[0] * inv + b0);
  o1.z = GELU(sr[1] * inv + b1); o1.w = GELU(si[1] * inv + b1);
  o2.x = GELU(sr[2] * inv + b2); o2.y = GELU(si[2] * inv + b2);
  o2.z = GELU(sr[3] * inv + b3); o2.w = GELU(si[3] * inv + b3);
  float* dst = out + (size_t)t * TWO_D + (size_t)f4 * 2;
  reinterpret_cast<float4*>(dst)[0] = o1;
  reinterpret_cast<float4*>(dst)[1] = o2;
}

// ---------------------------------------------------------------- launch
extern "C" void kernel_launch(void* const* d_in, const int* in_sizes, int n_in,
                              void* d_out, int out_size, void* d_ws, size_t ws_size,
                              hipStream_t stream) {
  const float* x    = (const float*)d_in[0];
  const float* gw   = (const float*)d_in[1];
  const float* w    = (const float*)d_in[2];
  const float* bias = (const float*)d_in[3];
  float* out = (float*)d_out;

  char* ws = (char*)d_ws;
  u16*   yrw     = (u16*)(ws);                  //  32 MiB (aliases scoresT)
  float* scoresT = (float*)(ws);                //   4 MiB (dead before k4)
  u16*   yiw     = (u16*)(ws + 33554432);       //  32 MiB
  int*   tidx    = (int*)(ws + 67108864);       //  128 KiB
  float* tscr    = (float*)(ws + 67239936);     //  128 KiB
  int*   counts  = (int*)(ws + 67371008);       //  64 KiB
  int*   entries = (int*)(ws + 67436544);       //   4 MiB
  u16*   wrT     = (u16*)(ws + 71630848);       //  32 MiB
  u16*   wiT     = (u16*)(ws + 105185280);      //  32 MiB  (end: 138,739,712)
  u16*   xrb     = (u16*)(ws + 138739712);      //  16 MiB  (preconv only)
  u16*   xib     = (u16*)(ws + 155516928);      //  16 MiB  (end: 172,294,144)

  const bool preconv = ws_size >= 172294144ull;

  hipMemsetAsync(counts, 0, B_T * sizeof(int), stream);
  if (preconv) {
    k13_fused<<<512 + NE * 128, 256, 0, stream>>>(x, gw, scoresT, xrb, xib, w, wrT, wiT);
    k2_topk<<<NE, 1024, 0, stream>>>(scoresT, tidx, tscr, counts, entries);
    k4_pre<<<1024, 256, 0, stream>>>(xrb, xib, tidx, tscr, wrT, wiT, yrw, yiw);
  } else {
    k13_fused<<<512 + NE * 128, 256, 0, stream>>>(x, gw, scoresT,
                                                  (u16*)(ws + 33554432),
                                                  (u16*)(ws + 33554432 + 16777216),
                                                  w, wrT, wiT);
    k2_topk<<<NE, 1024, 0, stream>>>(scoresT, tidx, tscr, counts, entries);
    k4_fb<<<1024, 256, 0, stream>>>(x, tidx, tscr, wrT, wiT, yrw, yiw);
  }
  k5_gather<<<B_T / 2, 256, 0, stream>>>(yrw, yiw, counts, entries, bias, out);
}